// Round 2
// baseline (1539.894 us; speedup 1.0000x reference)
//
#include <hip/hip_runtime.h>
#include <hip/hip_bf16.h>

// LSTM (all-tanh gates), B=128, T=1024, IN=512, UNITS=128.
//   k_wt   : W [512,512] f32 -> Wt bf16 [n][k] (transposed) in ws
//   k_ut   : U [128,512] f32 -> Ut f32 [col][k] (transposed) in ws
//   k_xc   : x f32 -> bf16 (if ws allows) so gemm stages A without repack
//   k_gemm : xW = x @ W, bf16 MFMA 16x16x32, out f32 (or bf16 if ws small)
//   k_scan : 128 WGs (one per batch elem); per step z = U^T h on the MFMA
//            pipe with U resident in VGPRs as hi/lo-split bf16 A-fragments,
//            h fed as B with col0=h_hi col1=h_lo (exact split product).

#define UNITS 128
#define IN_DIM 512
#define BATCH 128
#define SEQ 1024
#define GATES 512
#define M_ROWS (BATCH * SEQ)

typedef __attribute__((ext_vector_type(8))) short short8;
typedef __attribute__((ext_vector_type(4))) float floatx4;

__device__ __forceinline__ unsigned short f2bf(float f) {
    unsigned int x = __builtin_bit_cast(unsigned int, f);
    unsigned int r = (x + 0x7fffu + ((x >> 16) & 1u)) >> 16; // RNE
    return (unsigned short)r;
}
__device__ __forceinline__ float bf2f(unsigned short u) {
    unsigned int x = ((unsigned int)u) << 16;
    return __builtin_bit_cast(float, x);
}
__device__ __forceinline__ unsigned int pack2(float lo, float hi) {
    return (unsigned int)f2bf(lo) | ((unsigned int)f2bf(hi) << 16);
}

// tanh(x) = 1 - 2/(exp(2x)+1); clamp so exp stays finite. ~1e-7 abs error.
__device__ __forceinline__ float fast_tanh(float x) {
    float xc = fminf(12.0f, fmaxf(-12.0f, x));
    float e = __expf(2.0f * xc);
    return 1.0f - 2.0f * __builtin_amdgcn_rcpf(e + 1.0f);
}

// ---------------- W transpose + convert: Wt[n][k] = bf16(W[k][n]) ----------
__global__ void k_wt(const float* __restrict__ W, unsigned short* __restrict__ Wt) {
    int idx = blockIdx.x * 256 + threadIdx.x;
    int n = idx >> 9;
    int k = idx & 511;
    Wt[idx] = f2bf(W[k * 512 + n]);
}

// ---------------- U transpose: Ut[col][k] = U[k][col] (f32) ----------------
__global__ void k_ut(const float* __restrict__ U, float* __restrict__ Ut) {
    int idx = blockIdx.x * 256 + threadIdx.x; // 65536
    int col = idx >> 7;
    int k = idx & 127;
    Ut[idx] = U[k * 512 + col];
}

// ---------------- x f32 -> bf16 ----------------
__global__ void k_xc(const float* __restrict__ x, unsigned short* __restrict__ xb) {
    size_t i = ((size_t)blockIdx.x * 256 + threadIdx.x) * 8;
    float4 a = *(const float4*)(x + i);
    float4 b = *(const float4*)(x + i + 4);
    uint4 p;
    p.x = pack2(a.x, a.y); p.y = pack2(a.z, a.w);
    p.z = pack2(b.x, b.y); p.w = pack2(b.z, b.w);
    *(uint4*)(xb + i) = p;
}

// ---------------- GEMM: C[m][n] = sum_k A[m][k] * W[k][n] ------------------
// 128x128 block tile, BK=32, 256 threads (4 waves, 2x2 of 64x64), bf16 MFMA.
template <bool XWF32, bool ABF16>
__global__ void __launch_bounds__(256, 2)
k_gemm(const void* __restrict__ Ain, const unsigned short* __restrict__ Bt,
       void* __restrict__ Cout) {
    __shared__ __align__(16) unsigned short As[128 * 40];
    __shared__ __align__(16) unsigned short Bs[128 * 40];
    const int tid = threadIdx.x;
    const int m0 = blockIdx.y << 7;
    const int n0 = blockIdx.x << 7;
    const int l = tid & 63;
    const int w = tid >> 6;
    const int wr = (w >> 1) << 6;
    const int wc = (w & 1) << 6;
    const int lrow = l & 15;
    const int lq = l >> 4;

    floatx4 acc[4][4] = {};

    const int srow = tid >> 1;
    const int soff = (tid & 1) << 4;
    const float* apf = (const float*)Ain + (size_t)(m0 + srow) * 512 + soff;
    const unsigned short* apb = (const unsigned short*)Ain + (size_t)(m0 + srow) * 512 + soff;
    const unsigned short* bp = Bt + (size_t)(n0 + srow) * 512 + soff;
    unsigned short* as = &As[srow * 40 + soff];
    unsigned short* bs = &Bs[srow * 40 + soff];

    for (int k0 = 0; k0 < 512; k0 += 32) {
        uint4 pa0, pa1;
        if (ABF16) {
            pa0 = *(const uint4*)(apb + k0);
            pa1 = *(const uint4*)(apb + k0 + 8);
        } else {
            float4 a0 = *(const float4*)(apf + k0);
            float4 a1 = *(const float4*)(apf + k0 + 4);
            float4 a2 = *(const float4*)(apf + k0 + 8);
            float4 a3 = *(const float4*)(apf + k0 + 12);
            pa0.x = pack2(a0.x, a0.y); pa0.y = pack2(a0.z, a0.w);
            pa0.z = pack2(a1.x, a1.y); pa0.w = pack2(a1.z, a1.w);
            pa1.x = pack2(a2.x, a2.y); pa1.y = pack2(a2.z, a2.w);
            pa1.z = pack2(a3.x, a3.y); pa1.w = pack2(a3.z, a3.w);
        }
        uint4 b0 = *(const uint4*)(bp + k0);
        uint4 b1 = *(const uint4*)(bp + k0 + 8);
        __syncthreads();
        *(uint4*)as = pa0;
        *(uint4*)(as + 8) = pa1;
        *(uint4*)bs = b0;
        *(uint4*)(bs + 8) = b1;
        __syncthreads();
        short8 af[4], bfv[4];
#pragma unroll
        for (int mi = 0; mi < 4; ++mi)
            af[mi] = *(const short8*)&As[(wr + mi * 16 + lrow) * 40 + lq * 8];
#pragma unroll
        for (int ni = 0; ni < 4; ++ni)
            bfv[ni] = *(const short8*)&Bs[(wc + ni * 16 + lrow) * 40 + lq * 8];
#pragma unroll
        for (int mi = 0; mi < 4; ++mi)
#pragma unroll
            for (int ni = 0; ni < 4; ++ni)
                acc[mi][ni] = __builtin_amdgcn_mfma_f32_16x16x32_bf16(
                    af[mi], bfv[ni], acc[mi][ni], 0, 0, 0);
    }
#pragma unroll
    for (int mi = 0; mi < 4; ++mi) {
#pragma unroll
        for (int ni = 0; ni < 4; ++ni) {
            int row = m0 + wr + mi * 16 + lq * 4;
            int col = n0 + wc + ni * 16 + lrow;
            if (XWF32) {
                float* Cf = (float*)Cout;
#pragma unroll
                for (int r = 0; r < 4; ++r)
                    Cf[(size_t)(row + r) * 512 + col] = acc[mi][ni][r];
            } else {
                unsigned short* Cb = (unsigned short*)Cout;
#pragma unroll
                for (int r = 0; r < 4; ++r)
                    Cb[(size_t)(row + r) * 512 + col] = f2bf(acc[mi][ni][r]);
            }
        }
    }
}

// ---------------- recurrent scan: MFMA-based, one WG per batch element -----
// 512 threads = 8 waves. Wave w owns gate-tiles 4w..4w+3 (16 gate cols each).
// A-frag (resident in VGPRs): A[m][k] = U[k][g*16+m], hi/lo bf16 split.
// B-frag: col0 = h_hi, col1 = h_lo (bf16 split of f32 h); cols 2..15 zero.
// z[row] = C[row][0] + C[row][1] = (Uhi+Ulo)*(hhi+hlo) -- exact split product.
template <bool XWF32>
__global__ void __launch_bounds__(512, 2)
k_scan(const void* __restrict__ xwv, const float* __restrict__ Ut,
       const float* __restrict__ bias, float* __restrict__ out) {
    __shared__ __align__(16) unsigned short h2[2][128];
    __shared__ __align__(16) float z2[2][512];
    const int tid = threadIdx.x;
    const int bb = blockIdx.x;
    const int l = tid & 63;
    const int w = tid >> 6;
    const int m = l & 15; // row-in-tile (A) / col (B,C)
    const int q = l >> 4; // quad

    // ---- load U fragments once (hi/lo split), ~128 VGPRs resident ----
    short8 Ahi[4][4], Alo[4][4];
#pragma unroll
    for (int gi = 0; gi < 4; ++gi) {
        const int col = (w * 4 + gi) * 16 + m;
        const float* up = Ut + col * 128 + q * 8;
#pragma unroll
        for (int c = 0; c < 4; ++c) {
            float4 v0 = *(const float4*)(up + c * 32);
            float4 v1 = *(const float4*)(up + c * 32 + 4);
            float vv[8] = {v0.x, v0.y, v0.z, v0.w, v1.x, v1.y, v1.z, v1.w};
            short8 hi, lo;
#pragma unroll
            for (int j = 0; j < 8; ++j) {
                unsigned short hb = f2bf(vv[j]);
                hi[j] = (short)hb;
                lo[j] = (short)f2bf(vv[j] - bf2f(hb));
            }
            Ahi[gi][c] = hi;
            Alo[gi][c] = lo;
        }
    }

    if (tid < 256) ((unsigned short*)h2)[tid] = 0; // h = 0

    float c_st = 0.0f, h_out = 0.0f;
    float b4[4] = {}, xw4[4] = {};
    const float* xpf = nullptr;
    const unsigned short* xpb = nullptr;
    if (tid < UNITS) {
#pragma unroll
        for (int g = 0; g < 4; ++g) b4[g] = bias[tid + 128 * g];
        if (XWF32) {
            xpf = (const float*)xwv + (size_t)bb * SEQ * 512 + tid;
#pragma unroll
            for (int g = 0; g < 4; ++g) xw4[g] = xpf[128 * g];
        } else {
            xpb = (const unsigned short*)xwv + (size_t)bb * SEQ * 512 + tid;
#pragma unroll
            for (int g = 0; g < 4; ++g) xw4[g] = bf2f(xpb[128 * g]);
        }
    }
    __syncthreads();

    for (int t = 0; t < SEQ; ++t) {
        // B-fragments: 8 active lanes/wave (m<2), zeros elsewhere
        short8 bfr[4] = {};
        if (m < 2) {
#pragma unroll
            for (int c = 0; c < 4; ++c)
                bfr[c] = *(const short8*)&h2[m][c * 32 + q * 8];
        }
        floatx4 acc[4];
#pragma unroll
        for (int gi = 0; gi < 4; ++gi) {
            floatx4 a = {0.f, 0.f, 0.f, 0.f};
#pragma unroll
            for (int c = 0; c < 4; ++c)
                a = __builtin_amdgcn_mfma_f32_16x16x32_bf16(Ahi[gi][c], bfr[c], a, 0, 0, 0);
#pragma unroll
            for (int c = 0; c < 4; ++c)
                a = __builtin_amdgcn_mfma_f32_16x16x32_bf16(Alo[gi][c], bfr[c], a, 0, 0, 0);
            acc[gi] = a;
        }
        if (m < 2) { // C layout: col=lane&15, row=q*4+r
#pragma unroll
            for (int gi = 0; gi < 4; ++gi)
                *(floatx4*)&z2[m][(w * 4 + gi) * 16 + q * 4] = acc[gi];
        }
        // prefetch next step's xW while MFMA results land
        float xwn[4] = {};
        if (tid < UNITS && t + 1 < SEQ) {
#pragma unroll
            for (int g = 0; g < 4; ++g)
                xwn[g] = XWF32 ? xpf[(size_t)(t + 1) * 512 + 128 * g]
                               : bf2f(xpb[(size_t)(t + 1) * 512 + 128 * g]);
        }
        __syncthreads(); // z2 ready
        if (tid < UNITS) {
            float zg[4];
#pragma unroll
            for (int g = 0; g < 4; ++g)
                zg[g] = xw4[g] + b4[g] + z2[0][tid + 128 * g] + z2[1][tid + 128 * g];
            float gi_ = fast_tanh(zg[0]);
            float gf = fast_tanh(zg[1]);
            float gg = fast_tanh(zg[2]);
            float go = fast_tanh(zg[3]);
            c_st = fmaf(gf, c_st, gi_ * gg);
            h_out = go * fast_tanh(c_st);
            unsigned short hh = f2bf(h_out);
            h2[0][tid] = hh;
            h2[1][tid] = f2bf(h_out - bf2f(hh));
#pragma unroll
            for (int g = 0; g < 4; ++g) xw4[g] = xwn[g];
        }
        __syncthreads(); // h2 ready
    }
    if (tid < UNITS) out[bb * UNITS + tid] = h_out;
}

// ---------------------------------------------------------------------------
extern "C" void kernel_launch(void* const* d_in, const int* in_sizes, int n_in,
                              void* d_out, int out_size, void* d_ws, size_t ws_size,
                              hipStream_t stream) {
    const float* x = (const float*)d_in[0]; // [128,1024,512]
    const float* W = (const float*)d_in[1]; // [512,512]
    const float* U = (const float*)d_in[2]; // [128,512]
    const float* b = (const float*)d_in[3]; // [512]
    float* out = (float*)d_out;             // [128,128]

    char* ws = (char*)d_ws;
    unsigned short* Wt = (unsigned short*)ws;       // 512 KB
    float* Ut = (float*)(ws + 524288);              // 256 KB
    char* rest = ws + 524288 + 262144;
    const size_t base = 524288 + 262144;
    const size_t XW_F32 = (size_t)M_ROWS * 512 * 4;  // 256 MB
    const size_t XW_BF16 = XW_F32 / 2;               // 128 MB
    const size_t XB = (size_t)M_ROWS * 512 * 2;      // 128 MB

    k_wt<<<dim3(1024), dim3(256), 0, stream>>>(W, Wt);
    k_ut<<<dim3(256), dim3(256), 0, stream>>>(U, Ut);

    dim3 ggrid(4, 1024);
    if (ws_size >= base + XW_F32 + XB) {
        float* xw = (float*)rest;
        unsigned short* xb = (unsigned short*)(rest + XW_F32);
        k_xc<<<dim3(32768), dim3(256), 0, stream>>>(x, xb);
        k_gemm<true, true><<<ggrid, dim3(256), 0, stream>>>(xb, Wt, xw);
        k_scan<true><<<dim3(128), dim3(512), 0, stream>>>(xw, Ut, b, out);
    } else if (ws_size >= base + XW_F32) {
        float* xw = (float*)rest;
        k_gemm<true, false><<<ggrid, dim3(256), 0, stream>>>(x, Wt, xw);
        k_scan<true><<<dim3(128), dim3(512), 0, stream>>>(xw, Ut, b, out);
    } else if (ws_size >= base + XW_BF16 + XB) {
        unsigned short* xw = (unsigned short*)rest;
        unsigned short* xb = (unsigned short*)(rest + XW_BF16);
        k_xc<<<dim3(32768), dim3(256), 0, stream>>>(x, xb);
        k_gemm<false, true><<<ggrid, dim3(256), 0, stream>>>(xb, Wt, xw);
        k_scan<false><<<dim3(128), dim3(512), 0, stream>>>(xw, Ut, b, out);
    } else {
        unsigned short* xw = (unsigned short*)rest;
        k_gemm<false, false><<<ggrid, dim3(256), 0, stream>>>(x, Wt, xw);
        k_scan<false><<<dim3(128), dim3(512), 0, stream>>>(xw, Ut, b, out);
    }
}

// Round 3
// 1339.487 us; speedup vs baseline: 1.1496x; 1.1496x over previous
//
#include <hip/hip_runtime.h>
#include <hip/hip_bf16.h>

// LSTM (all-tanh gates), B=128, T=1024, IN=512, UNITS=128.
//   k_wt    : W [512,512] f32 -> Wt bf16 [n][k] (transposed) in ws
//   k_ut    : U [128,512] f32 -> Ut f32 [col][k] (transposed) in ws
//   k_gemm2 : xW = x @ W. 64x512 blocks: A read once (f32->bf16 repack in
//             kernel), B (512KB) direct L2->reg, bf16 MFMA, f32 out.
//   k_scan  : 128 WGs (one per batch elem), 8 waves. Per step:
//             A-operand = h (row0=h_hi,row1=h_lo), B-operand = U resident in
//             VGPRs (hi/lo bf16 split, cols = units). z = C[0][n]+C[1][n]
//             lands in ONE lane per unit -> no z-LDS round trip, 1 barrier
//             per step, h2 parity double-buffered, xW prefetch 4 steps deep.

#define UNITS 128
#define IN_DIM 512
#define BATCH 128
#define SEQ 1024
#define GATES 512
#define M_ROWS (BATCH * SEQ)

typedef __attribute__((ext_vector_type(8))) short short8;
typedef __attribute__((ext_vector_type(4))) float floatx4;

__device__ __forceinline__ unsigned short f2bf(float f) {
    unsigned int x = __builtin_bit_cast(unsigned int, f);
    unsigned int r = (x + 0x7fffu + ((x >> 16) & 1u)) >> 16; // RNE
    return (unsigned short)r;
}
__device__ __forceinline__ float bf2f(unsigned short u) {
    unsigned int x = ((unsigned int)u) << 16;
    return __builtin_bit_cast(float, x);
}
__device__ __forceinline__ unsigned int pack2(float lo, float hi) {
    return (unsigned int)f2bf(lo) | ((unsigned int)f2bf(hi) << 16);
}

// tanh(x) = 1 - 2/(exp(2x)+1); clamp so exp stays finite.
__device__ __forceinline__ float fast_tanh(float x) {
    float xc = fminf(12.0f, fmaxf(-12.0f, x));
    float e = __expf(2.0f * xc);
    return 1.0f - 2.0f * __builtin_amdgcn_rcpf(e + 1.0f);
}

// ---------------- W transpose + convert: Wt[n][k] = bf16(W[k][n]) ----------
__global__ void k_wt(const float* __restrict__ W, unsigned short* __restrict__ Wt) {
    int idx = blockIdx.x * 256 + threadIdx.x;
    int n = idx >> 9;
    int k = idx & 511;
    Wt[idx] = f2bf(W[k * 512 + n]);
}

// ---------------- U transpose: Ut[col][k] = U[k][col] (f32) ----------------
__global__ void k_ut(const float* __restrict__ U, float* __restrict__ Ut) {
    int idx = blockIdx.x * 256 + threadIdx.x; // 65536
    int col = idx >> 7;
    int k = idx & 127;
    Ut[idx] = U[k * 512 + col];
}

// ---------------- GEMM v2: C[m][n] = sum_k A[m][k] * W[k][n] --------------
// Block = 64 rows x 512 cols, 512 threads (8 waves, wave w -> cols [64w,64w+64)).
// A staged via LDS (f32->bf16 repack); B frags loaded direct from L2 each iter.
template <bool XWF32>
__global__ void __launch_bounds__(512, 2)
k_gemm2(const float* __restrict__ A, const unsigned short* __restrict__ Bt,
        void* __restrict__ Cout) {
    __shared__ __align__(16) unsigned short As[64 * 40];
    const int tid = threadIdx.x;
    const int m0 = blockIdx.x << 6;
    const int l = tid & 63;
    const int w = tid >> 6;
    const int lrow = l & 15;
    const int lq = l >> 4;

    // staging: thread -> (row, 4-elem chunk)
    const int srow = tid >> 3;
    const int scol = (tid & 7) << 2;
    const float* ap = A + (size_t)(m0 + srow) * 512 + scol;
    unsigned short* as = &As[srow * 40 + scol];
    const unsigned short* bp = Bt + (size_t)((w << 6) + lrow) * 512 + lq * 8;

    floatx4 acc[4][4] = {};

    float4 a_nx = *(const float4*)ap;
    short8 b_nx[4];
#pragma unroll
    for (int ni = 0; ni < 4; ++ni)
        b_nx[ni] = *(const short8*)(bp + ni * (16 * 512));

    for (int k0 = 0; k0 < 512; k0 += 32) {
        float4 a_c = a_nx;
        short8 b_c[4];
#pragma unroll
        for (int ni = 0; ni < 4; ++ni) b_c[ni] = b_nx[ni];
        __syncthreads(); // previous iteration's As readers done
        uint2 pa;
        pa.x = pack2(a_c.x, a_c.y);
        pa.y = pack2(a_c.z, a_c.w);
        *(uint2*)as = pa;
        __syncthreads(); // As ready
        if (k0 + 32 < 512) {
            a_nx = *(const float4*)(ap + k0 + 32);
#pragma unroll
            for (int ni = 0; ni < 4; ++ni)
                b_nx[ni] = *(const short8*)(bp + ni * (16 * 512) + k0 + 32);
        }
        short8 af[4];
#pragma unroll
        for (int mi = 0; mi < 4; ++mi)
            af[mi] = *(const short8*)&As[(mi * 16 + lrow) * 40 + lq * 8];
#pragma unroll
        for (int mi = 0; mi < 4; ++mi)
#pragma unroll
            for (int ni = 0; ni < 4; ++ni)
                acc[mi][ni] = __builtin_amdgcn_mfma_f32_16x16x32_bf16(
                    af[mi], b_c[ni], acc[mi][ni], 0, 0, 0);
    }
    // epilogue: C/D layout col=lane&15, row=(lane>>4)*4+r
#pragma unroll
    for (int mi = 0; mi < 4; ++mi) {
#pragma unroll
        for (int ni = 0; ni < 4; ++ni) {
            int row = m0 + mi * 16 + lq * 4;
            int col = (w << 6) + ni * 16 + lrow;
            if (XWF32) {
                float* Cf = (float*)Cout;
#pragma unroll
                for (int r = 0; r < 4; ++r)
                    Cf[(size_t)(row + r) * 512 + col] = acc[mi][ni][r];
            } else {
                unsigned short* Cb = (unsigned short*)Cout;
#pragma unroll
                for (int r = 0; r < 4; ++r)
                    Cb[(size_t)(row + r) * 512 + col] = f2bf(acc[mi][ni][r]);
            }
        }
    }
}

// ---------------- recurrent scan ------------------------------------------
// Wave w owns units [16w, 16w+16). B-operand tile g (gate g): B[k][n] =
// U[k][g*128 + 16w + n], hi/lo split, resident in VGPRs. A-operand: row0 =
// h_hi, row1 = h_lo (rows 2..15 duplicates, ignored). z for unit 16w+n =
// acc[0]+acc[1] at lane n (q=0). One barrier/step; h2 double-buffered.
#define XW_LOAD(T, g)                                                          \
    (XWF32 ? xwf[(size_t)(T) * 512 + (g) * 128]                                \
           : bf2f(xwb[(size_t)(T) * 512 + (g) * 128]))

#define LSTM_STEP(T, S, P)                                                     \
    {                                                                          \
        short8 af[4];                                                          \
        _Pragma("unroll") for (int c = 0; c < 4; ++c)                          \
            af[c] = *(const short8*)&h2[P][n & 1][c * 32 + q * 8];             \
        floatx4 zsum[4];                                                       \
        _Pragma("unroll") for (int g = 0; g < 4; ++g) {                        \
            floatx4 ah = {0.f, 0.f, 0.f, 0.f};                                 \
            floatx4 al = {0.f, 0.f, 0.f, 0.f};                                 \
            _Pragma("unroll") for (int c = 0; c < 4; ++c)                      \
                ah = __builtin_amdgcn_mfma_f32_16x16x32_bf16(af[c], Bhi[g][c], \
                                                             ah, 0, 0, 0);     \
            _Pragma("unroll") for (int c = 0; c < 4; ++c)                      \
                al = __builtin_amdgcn_mfma_f32_16x16x32_bf16(af[c], Blo[g][c], \
                                                             al, 0, 0, 0);     \
            zsum[g] = ah + al;                                                 \
        }                                                                      \
        float zz[4];                                                           \
        _Pragma("unroll") for (int g = 0; g < 4; ++g)                          \
            zz[g] = xbuf[S][g] + b4[g] + (zsum[g][0] + zsum[g][1]);            \
        if ((T) + 4 < SEQ) {                                                   \
            _Pragma("unroll") for (int g = 0; g < 4; ++g)                      \
                xbuf[S][g] = XW_LOAD((T) + 4, g);                              \
        }                                                                      \
        float gi_ = fast_tanh(zz[0]);                                          \
        float gf_ = fast_tanh(zz[1]);                                          \
        float gg_ = fast_tanh(zz[2]);                                          \
        float go_ = fast_tanh(zz[3]);                                          \
        c_st = fmaf(gf_, c_st, gi_ * gg_);                                     \
        h_out = go_ * fast_tanh(c_st);                                         \
        unsigned short hh = f2bf(h_out);                                       \
        unsigned short hl = f2bf(h_out - bf2f(hh));                            \
        if (l < 16) {                                                          \
            h2[(P) ^ 1][0][(w << 4) + n] = hh;                                 \
            h2[(P) ^ 1][1][(w << 4) + n] = hl;                                 \
        }                                                                      \
        __syncthreads();                                                       \
    }

template <bool XWF32>
__global__ void __launch_bounds__(512, 2)
k_scan(const void* __restrict__ xwv, const float* __restrict__ Ut,
       const float* __restrict__ bias, float* __restrict__ out) {
    __shared__ __align__(16) unsigned short h2[2][2][128]; // [parity][hi/lo][unit]
    const int tid = threadIdx.x;
    const int bb = blockIdx.x;
    const int l = tid & 63;
    const int w = tid >> 6;
    const int n = l & 15; // unit-in-wave (B col / C col)
    const int q = l >> 4; // k-quad

    // ---- U as B-operand fragments (hi/lo split), resident ~128 VGPRs ----
    short8 Bhi[4][4], Blo[4][4];
#pragma unroll
    for (int g = 0; g < 4; ++g) {
        const float* up = Ut + (g * 128 + (w << 4) + n) * 128 + q * 8;
#pragma unroll
        for (int c = 0; c < 4; ++c) {
            float4 v0 = *(const float4*)(up + c * 32);
            float4 v1 = *(const float4*)(up + c * 32 + 4);
            float vv[8] = {v0.x, v0.y, v0.z, v0.w, v1.x, v1.y, v1.z, v1.w};
            short8 hi, lo;
#pragma unroll
            for (int j = 0; j < 8; ++j) {
                unsigned short hb = f2bf(vv[j]);
                hi[j] = (short)hb;
                lo[j] = (short)f2bf(vv[j] - bf2f(hb));
            }
            Bhi[g][c] = hi;
            Blo[g][c] = lo;
        }
    }

    if (tid < 256) ((unsigned int*)h2)[tid] = 0; // zero both parities

    float b4[4];
#pragma unroll
    for (int g = 0; g < 4; ++g) b4[g] = bias[g * 128 + (w << 4) + n];

    const float* xwf = (const float*)xwv + (size_t)bb * SEQ * 512 + (w << 4) + n;
    const unsigned short* xwb =
        (const unsigned short*)xwv + (size_t)bb * SEQ * 512 + (w << 4) + n;

    float xbuf[4][4]; // 4-step-deep prefetch pipeline
#pragma unroll
    for (int s = 0; s < 4; ++s)
#pragma unroll
        for (int g = 0; g < 4; ++g) xbuf[s][g] = XW_LOAD(s, g);

    float c_st = 0.0f, h_out = 0.0f;
    __syncthreads();

    for (int t4 = 0; t4 < SEQ; t4 += 4) {
        LSTM_STEP(t4 + 0, 0, 0)
        LSTM_STEP(t4 + 1, 1, 1)
        LSTM_STEP(t4 + 2, 2, 0)
        LSTM_STEP(t4 + 3, 3, 1)
    }
    if (l < 16) out[bb * UNITS + (w << 4) + n] = h_out;
}

// ---------------------------------------------------------------------------
extern "C" void kernel_launch(void* const* d_in, const int* in_sizes, int n_in,
                              void* d_out, int out_size, void* d_ws, size_t ws_size,
                              hipStream_t stream) {
    const float* x = (const float*)d_in[0]; // [128,1024,512]
    const float* W = (const float*)d_in[1]; // [512,512]
    const float* U = (const float*)d_in[2]; // [128,512]
    const float* b = (const float*)d_in[3]; // [512]
    float* out = (float*)d_out;             // [128,128]

    char* ws = (char*)d_ws;
    unsigned short* Wt = (unsigned short*)ws; // 512 KB
    float* Ut = (float*)(ws + 524288);        // 256 KB
    char* rest = ws + 524288 + 262144;
    const size_t base = 524288 + 262144;
    const size_t XW_F32 = (size_t)M_ROWS * 512 * 4; // 256 MB

    k_wt<<<dim3(1024), dim3(256), 0, stream>>>(W, Wt);
    k_ut<<<dim3(256), dim3(256), 0, stream>>>(U, Ut);

    dim3 ggrid(M_ROWS / 64); // 2048 blocks
    if (ws_size >= base + XW_F32) {
        float* xw = (float*)rest;
        k_gemm2<true><<<ggrid, dim3(512), 0, stream>>>(x, Wt, xw);
        k_scan<true><<<dim3(128), dim3(512), 0, stream>>>(xw, Ut, b, out);
    } else {
        unsigned short* xw = (unsigned short*)rest;
        k_gemm2<false><<<ggrid, dim3(512), 0, stream>>>(x, Wt, xw);
        k_scan<false><<<dim3(128), dim3(512), 0, stream>>>(xw, Ut, b, out);
    }
}

// Round 4
// 1319.739 us; speedup vs baseline: 1.1668x; 1.0150x over previous
//
#include <hip/hip_runtime.h>
#include <hip/hip_bf16.h>

// LSTM (all-tanh gates), B=128, T=1024, IN=512, UNITS=128.
//   k_wt    : W [512,512] f32 -> Wt bf16 [n][k] (transposed) in ws
//   k_ut    : U [128,512] f32 -> Ut f32 [col][k] (transposed) in ws
//   k_gemm2 : xW = x @ W. 64x512 blocks, dbuf LDS A-tile, ONE lds-only
//             barrier per K-iter (CK block_sync_lds pattern: lgkmcnt(0)+
//             s_barrier, NO vmcnt drain), depth-2 global prefetch A+B.
//   k_scan  : 128 WGs (one per batch elem), 8 waves. Per step one lds-only
//             barrier; xW prefetch 4 steps deep rides across barriers.
//             A-operand = h (alternating hi/lo rows), B-operand = U resident
//             in VGPRs (hi/lo bf16 split: exact product, ~f32 accuracy).

#define UNITS 128
#define IN_DIM 512
#define BATCH 128
#define SEQ 1024
#define GATES 512
#define M_ROWS (BATCH * SEQ)

typedef __attribute__((ext_vector_type(8))) short short8;
typedef __attribute__((ext_vector_type(4))) float floatx4;

__device__ __forceinline__ unsigned short f2bf(float f) {
    unsigned int x = __builtin_bit_cast(unsigned int, f);
    unsigned int r = (x + 0x7fffu + ((x >> 16) & 1u)) >> 16; // RNE
    return (unsigned short)r;
}
__device__ __forceinline__ float bf2f(unsigned short u) {
    unsigned int x = ((unsigned int)u) << 16;
    return __builtin_bit_cast(float, x);
}
__device__ __forceinline__ unsigned int pack2(float lo, float hi) {
    return (unsigned int)f2bf(lo) | ((unsigned int)f2bf(hi) << 16);
}

// LDS-only barrier: drains lgkmcnt but lets global loads ride across.
__device__ __forceinline__ void lds_barrier() {
    asm volatile("s_waitcnt lgkmcnt(0)\n\ts_barrier" ::: "memory");
}

// tanh(x) = 1 - 2/(exp(2x)+1); clamp so exp stays finite.
__device__ __forceinline__ float fast_tanh(float x) {
    float xc = fminf(12.0f, fmaxf(-12.0f, x));
    float e = __expf(2.0f * xc);
    return 1.0f - 2.0f * __builtin_amdgcn_rcpf(e + 1.0f);
}

// ---------------- W transpose + convert: Wt[n][k] = bf16(W[k][n]) ----------
__global__ void k_wt(const float* __restrict__ W, unsigned short* __restrict__ Wt) {
    int idx = blockIdx.x * 256 + threadIdx.x;
    int n = idx >> 9;
    int k = idx & 511;
    Wt[idx] = f2bf(W[k * 512 + n]);
}

// ---------------- U transpose: Ut[col][k] = U[k][col] (f32) ----------------
__global__ void k_ut(const float* __restrict__ U, float* __restrict__ Ut) {
    int idx = blockIdx.x * 256 + threadIdx.x; // 65536
    int col = idx >> 7;
    int k = idx & 127;
    Ut[idx] = U[k * 512 + col];
}

// ---------------- GEMM v2: C[m][n] = sum_k A[m][k] * W[k][n] --------------
// Block = 64 rows x 512 cols, 512 threads (8 waves; wave w -> cols [64w,64w+64)).
// A staged via dbuf LDS (f32->bf16 repack); B frags direct L2->reg.
template <bool XWF32>
__global__ void __launch_bounds__(512, 2)
k_gemm2(const float* __restrict__ A, const unsigned short* __restrict__ Bt,
        void* __restrict__ Cout) {
    __shared__ __align__(16) unsigned short As[2][64 * 40];
    const int tid = threadIdx.x;
    const int m0 = blockIdx.x << 6;
    const int l = tid & 63;
    const int w = tid >> 6;
    const int lrow = l & 15;
    const int lq = l >> 4;

    const int srow = tid >> 3;       // 64 rows, 8 threads/row
    const int scol = (tid & 7) << 2; // 4-float chunk
    const float* ap = A + (size_t)(m0 + srow) * 512 + scol;
    unsigned short* as = &As[0][srow * 40 + scol];
    const unsigned short* bp = Bt + (size_t)((w << 6) + lrow) * 512 + lq * 8;

    floatx4 acc[4][4] = {};

    // depth-2 prefetch pipeline
    float4 a_pf[2];
    short8 b_pf[2][4];
    a_pf[0] = *(const float4*)ap;
    a_pf[1] = *(const float4*)(ap + 32);
#pragma unroll
    for (int ni = 0; ni < 4; ++ni) {
        b_pf[0][ni] = *(const short8*)(bp + ni * 8192);
        b_pf[1][ni] = *(const short8*)(bp + ni * 8192 + 32);
    }

    for (int it = 0; it < 16; ++it) {
        const int buf = it & 1;
        float4 a_c = a_pf[buf];
        short8 b_c[4];
#pragma unroll
        for (int ni = 0; ni < 4; ++ni) b_c[ni] = b_pf[buf][ni];
        uint2 pa;
        pa.x = pack2(a_c.x, a_c.y);
        pa.y = pack2(a_c.z, a_c.w);
        *(uint2*)(as + buf * (64 * 40)) = pa;
        lds_barrier(); // writes visible; reads of this buf from it-2 fenced at it-1
        if (it + 2 < 16) {
            a_pf[buf] = *(const float4*)(ap + it * 32 + 64);
#pragma unroll
            for (int ni = 0; ni < 4; ++ni)
                b_pf[buf][ni] = *(const short8*)(bp + ni * 8192 + it * 32 + 64);
        }
        short8 af[4];
#pragma unroll
        for (int mi = 0; mi < 4; ++mi)
            af[mi] = *(const short8*)&As[buf][(mi * 16 + lrow) * 40 + lq * 8];
#pragma unroll
        for (int mi = 0; mi < 4; ++mi)
#pragma unroll
            for (int ni = 0; ni < 4; ++ni)
                acc[mi][ni] = __builtin_amdgcn_mfma_f32_16x16x32_bf16(
                    af[mi], b_c[ni], acc[mi][ni], 0, 0, 0);
    }
    // epilogue: C/D layout col=lane&15, row=(lane>>4)*4+r
#pragma unroll
    for (int mi = 0; mi < 4; ++mi) {
#pragma unroll
        for (int ni = 0; ni < 4; ++ni) {
            int row = m0 + mi * 16 + lq * 4;
            int col = (w << 6) + ni * 16 + lrow;
            if (XWF32) {
                float* Cf = (float*)Cout;
#pragma unroll
                for (int r = 0; r < 4; ++r)
                    Cf[(size_t)(row + r) * 512 + col] = acc[mi][ni][r];
            } else {
                unsigned short* Cb = (unsigned short*)Cout;
#pragma unroll
                for (int r = 0; r < 4; ++r)
                    Cb[(size_t)(row + r) * 512 + col] = f2bf(acc[mi][ni][r]);
            }
        }
    }
}

// ---------------- recurrent scan ------------------------------------------
// Wave w owns units [16w,16w+16). B tile g: B[k][n] = U[k][g*128+16w+n],
// hi/lo split resident in VGPRs. A rows alternate h_hi/h_lo (dup x4 by quad)
// -> z = acc[0]+acc[1] valid in every lane; gate phase on lanes l<16.
#define XW_LOAD(T, g)                                                          \
    (XWF32 ? xwf[(size_t)(T) * 512 + (g) * 128]                                \
           : bf2f(xwb[(size_t)(T) * 512 + (g) * 128]))

#define LSTM_STEP(T, S, P)                                                     \
    {                                                                          \
        short8 af[4];                                                          \
        _Pragma("unroll") for (int c = 0; c < 4; ++c)                          \
            af[c] = *(const short8*)&h2[P][n & 1][c * 32 + q * 8];             \
        floatx4 zsum[4];                                                       \
        _Pragma("unroll") for (int g = 0; g < 4; ++g) {                        \
            floatx4 ah = {0.f, 0.f, 0.f, 0.f};                                 \
            floatx4 al = {0.f, 0.f, 0.f, 0.f};                                 \
            _Pragma("unroll") for (int c = 0; c < 4; ++c)                      \
                ah = __builtin_amdgcn_mfma_f32_16x16x32_bf16(af[c], Bhi[g][c], \
                                                             ah, 0, 0, 0);     \
            _Pragma("unroll") for (int c = 0; c < 4; ++c)                      \
                al = __builtin_amdgcn_mfma_f32_16x16x32_bf16(af[c], Blo[g][c], \
                                                             al, 0, 0, 0);     \
            zsum[g] = ah + al;                                                 \
        }                                                                      \
        float zz[4];                                                           \
        _Pragma("unroll") for (int g = 0; g < 4; ++g)                          \
            zz[g] = xbuf[S][g] + b4[g] + (zsum[g][0] + zsum[g][1]);            \
        if (l < 16 && (T) + 4 < SEQ) {                                         \
            _Pragma("unroll") for (int g = 0; g < 4; ++g)                      \
                xbuf[S][g] = XW_LOAD((T) + 4, g);                              \
        }                                                                      \
        float gi_ = fast_tanh(zz[0]);                                          \
        float gf_ = fast_tanh(zz[1]);                                          \
        float gg_ = fast_tanh(zz[2]);                                          \
        float go_ = fast_tanh(zz[3]);                                          \
        c_st = fmaf(gf_, c_st, gi_ * gg_);                                     \
        h_out = go_ * fast_tanh(c_st);                                         \
        unsigned short hh = f2bf(h_out);                                       \
        unsigned short hl = f2bf(h_out - bf2f(hh));                            \
        if (l < 16) {                                                          \
            h2[(P) ^ 1][0][u16] = hh;                                          \
            h2[(P) ^ 1][1][u16] = hl;                                          \
        }                                                                      \
        lds_barrier();                                                         \
    }

template <bool XWF32>
__global__ void __launch_bounds__(512, 2)
k_scan(const void* __restrict__ xwv, const float* __restrict__ Ut,
       const float* __restrict__ bias, float* __restrict__ out) {
    __shared__ __align__(16) unsigned short h2[2][2][136]; // [parity][hi/lo][unit+pad]
    const int tid = threadIdx.x;
    const int bb = blockIdx.x;
    const int l = tid & 63;
    const int w = tid >> 6;
    const int n = l & 15; // unit-in-wave (B col / C col) / A row
    const int q = l >> 4; // k-quad
    const int u16 = (w << 4) + n;

    // ---- U as B-operand fragments (hi/lo split), resident ~128 VGPRs ----
    short8 Bhi[4][4], Blo[4][4];
#pragma unroll
    for (int g = 0; g < 4; ++g) {
        const float* up = Ut + (g * 128 + u16) * 128 + q * 8;
#pragma unroll
        for (int c = 0; c < 4; ++c) {
            float4 v0 = *(const float4*)(up + c * 32);
            float4 v1 = *(const float4*)(up + c * 32 + 4);
            float vv[8] = {v0.x, v0.y, v0.z, v0.w, v1.x, v1.y, v1.z, v1.w};
            short8 hi, lo;
#pragma unroll
            for (int j = 0; j < 8; ++j) {
                unsigned short hb = f2bf(vv[j]);
                hi[j] = (short)hb;
                lo[j] = (short)f2bf(vv[j] - bf2f(hb));
            }
            Bhi[g][c] = hi;
            Blo[g][c] = lo;
        }
    }

    if (tid < 272) ((unsigned int*)h2)[tid] = 0; // zero both parities (incl pad)

    float b4[4];
#pragma unroll
    for (int g = 0; g < 4; ++g) b4[g] = bias[g * 128 + u16];

    const float* xwf = (const float*)xwv + (size_t)bb * SEQ * 512 + u16;
    const unsigned short* xwb =
        (const unsigned short*)xwv + (size_t)bb * SEQ * 512 + u16;

    float xbuf[4][4]; // 4-step-deep prefetch pipeline (lanes l<16 only)
    if (l < 16) {
#pragma unroll
        for (int s = 0; s < 4; ++s)
#pragma unroll
            for (int g = 0; g < 4; ++g) xbuf[s][g] = XW_LOAD(s, g);
    }

    float c_st = 0.0f, h_out = 0.0f;
    lds_barrier();

    for (int t4 = 0; t4 < SEQ; t4 += 4) {
        LSTM_STEP(t4 + 0, 0, 0)
        LSTM_STEP(t4 + 1, 1, 1)
        LSTM_STEP(t4 + 2, 2, 0)
        LSTM_STEP(t4 + 3, 3, 1)
    }
    if (l < 16) out[bb * UNITS + u16] = h_out;
}

// ---------------------------------------------------------------------------
extern "C" void kernel_launch(void* const* d_in, const int* in_sizes, int n_in,
                              void* d_out, int out_size, void* d_ws, size_t ws_size,
                              hipStream_t stream) {
    const float* x = (const float*)d_in[0]; // [128,1024,512]
    const float* W = (const float*)d_in[1]; // [512,512]
    const float* U = (const float*)d_in[2]; // [128,512]
    const float* b = (const float*)d_in[3]; // [512]
    float* out = (float*)d_out;             // [128,128]

    char* ws = (char*)d_ws;
    unsigned short* Wt = (unsigned short*)ws; // 512 KB
    float* Ut = (float*)(ws + 524288);        // 256 KB
    char* rest = ws + 524288 + 262144;
    const size_t base = 524288 + 262144;
    const size_t XW_F32 = (size_t)M_ROWS * 512 * 4; // 256 MB

    k_wt<<<dim3(1024), dim3(256), 0, stream>>>(W, Wt);
    k_ut<<<dim3(256), dim3(256), 0, stream>>>(U, Ut);

    dim3 ggrid(M_ROWS / 64); // 2048 blocks
    if (ws_size >= base + XW_F32) {
        float* xw = (float*)rest;
        k_gemm2<true><<<ggrid, dim3(512), 0, stream>>>(x, Wt, xw);
        k_scan<true><<<dim3(128), dim3(512), 0, stream>>>(xw, Ut, b, out);
    } else {
        unsigned short* xw = (unsigned short*)rest;
        k_gemm2<false><<<ggrid, dim3(512), 0, stream>>>(x, Wt, xw);
        k_scan<false><<<dim3(128), dim3(512), 0, stream>>>(xw, Ut, b, out);
    }
}